// Round 4
// baseline (953.261 us; speedup 1.0000x reference)
//
#include <hip/hip_runtime.h>
#include <hip/hip_bf16.h>
#include <math.h>

// Problem constants (from reference setup_inputs)
#define BZ   8      // batch
#define DD   512    // z feature dim = H*dh
#define LL   2048   // sequence
#define HH   8      // heads
#define MM   1024   // codes per head
#define DH   64     // code dim
#define NN   (BZ * LL)          // 16384 rows per head
#define TOTAL_ELEMS (HH * NN * DH)   // 8388608, for the mean

// d_out layout (floats): [z_q (8388608)] [vq_loss (1)] [indices (131072)] [codebooks (524288)]
#define OFF_ZQ   0
#define OFF_LOSS 8388608
#define OFF_IDX  8388609
#define OFF_CB   8519681

// d_ws layout (floats): [sums (524288)] [counts (8192)] [sse (1)]
#define WS_SUMS   0
#define WS_COUNTS 524288
#define WS_SSE    532480
#define WS_FLOATS 532481

// R3 lesson: asm pins alone -> RA spilled zr to scratch (VGPR stayed 52),
// because __launch_bounds__ only sets the occupancy MINIMUM and the
// scheduler still targets 8 waves/EU. amdgpu_waves_per_eu(4,4) pins the
// MAXIMUM too -> RA budget 512/4 = 128 VGPRs, zr[64] can stay resident.
// Occupancy is grid-limited to 2 blocks/CU anyway, so the cap is free.
__global__ __launch_bounds__(256)
__attribute__((amdgpu_waves_per_eu(4, 4)))
void vq_assign_kernel(
    const float* __restrict__ z,          // [B, D, L]
    const float* __restrict__ cb,         // [H, M, DH]
    float* __restrict__ zq_out,           // [B, D, L]
    float* __restrict__ idx_out,          // [B, H, L] as float
    float* __restrict__ sums,             // [H, M, DH]
    float* __restrict__ counts,           // [H, M]
    float* __restrict__ sse)              // [1]
{
    const int n = blockIdx.x * 256 + threadIdx.x;   // n in [0, NN)
    const int h = blockIdx.y;
    const int b = n >> 11;          // n / LL
    const int l = n & (LL - 1);     // n % LL

    // Load this row's z vector into registers. z_split[h,n,k] = z[b, h*64+k, l]
    const float* __restrict__ zp = z + ((size_t)(b * DD + h * DH) * LL + l);
    float zr[DH];
#pragma unroll
    for (int k = 0; k < DH; ++k) zr[k] = zp[(size_t)k * LL];
    // Pin: forbid remat/sinking of the z-row loads into the scan loop.
#pragma unroll
    for (int k = 0; k < DH; ++k) asm volatile("" : "+v"(zr[k]));

    const float* __restrict__ cbh = cb + (size_t)h * MM * DH;

    // fp32 scan for top-2 (4 independent accumulator chains for ILP).
    // m-loop NOT unrolled: one codebook row = 64 SGPRs; unroll-by-2 would
    // exceed the SGPR file and force de-scalarization.
    float b1 = -1e30f, b2 = -1e30f;
    int i1 = 0, i2 = 0;
#pragma unroll 1
    for (int m = 0; m < MM; ++m) {
        const float* __restrict__ c = cbh + m * DH;   // wave-uniform address -> s_load
        float a0 = 0.f, a1 = 0.f, a2 = 0.f, a3 = 0.f;
#pragma unroll
        for (int k = 0; k < DH; k += 4) {
            a0 = fmaf(zr[k + 0], c[k + 0], a0);
            a1 = fmaf(zr[k + 1], c[k + 1], a1);
            a2 = fmaf(zr[k + 2], c[k + 2], a2);
            a3 = fmaf(zr[k + 3], c[k + 3], a3);
        }
        const float s = (a0 + a1) + (a2 + a3);
        // Branchless top-2 maintenance (v_cndmask chains, no divergence).
        const bool gt1 = s > b1;
        const bool gt2 = s > b2;
        b2 = gt1 ? b1 : (gt2 ? s : b2);
        i2 = gt1 ? i1 : (gt2 ? m : i2);
        b1 = gt1 ? s : b1;
        i1 = gt1 ? m : i1;
    }

    // fp64 refinement of the two candidates (resolves fp32 near-ties exactly).
    const float* __restrict__ c1 = cbh + i1 * DH;
    const float* __restrict__ c2 = cbh + i2 * DH;
    double d1 = 0.0, d2 = 0.0;
#pragma unroll
    for (int k = 0; k < DH; ++k) {
        d1 = fma((double)zr[k], (double)c1[k], d1);
        d2 = fma((double)zr[k], (double)c2[k], d2);
    }
    // argmax takes first occurrence on exact tie
    const int best = (d2 > d1 || (d2 == d1 && i2 < i1)) ? i2 : i1;

    // Outputs: quantized vector, squared error, segment sums.
    const float* __restrict__ cq = cbh + best * DH;
    float* __restrict__ zqp = zq_out + ((size_t)(b * DD + h * DH) * LL + l);
    float* __restrict__ srow = sums + ((size_t)h * MM + best) * DH;
    float err = 0.f;
#pragma unroll
    for (int k = 0; k < DH; ++k) {
        const float q = cq[k];
        zqp[(size_t)k * LL] = q;
        const float dk = zr[k] - q;
        err = fmaf(dk, dk, err);
        atomicAdd(&srow[k], zr[k]);
    }
    atomicAdd(&counts[h * MM + best], 1.0f);
    idx_out[((size_t)b * HH + h) * LL + l] = (float)best;

    // wave-level reduce of err, then one atomic per wave
#pragma unroll
    for (int off = 32; off; off >>= 1) err += __shfl_xor(err, off, 64);
    if ((threadIdx.x & 63) == 0) atomicAdd(sse, err);
}

__global__ __launch_bounds__(256) void vq_update_kernel(
    const float* __restrict__ cb,       // [H, M, DH]
    const float* __restrict__ sums,
    const float* __restrict__ counts,
    const float* __restrict__ sse,
    float* __restrict__ cb_out,         // [H, M, DH]
    float* __restrict__ loss_out)       // [1]
{
    if (blockIdx.x == 0 && threadIdx.x == 0) {
        loss_out[0] = 1.25f * sse[0] / (float)TOTAL_ELEMS;
    }
    const int row  = blockIdx.x * 4 + (threadIdx.x >> 6);   // (h*MM + m), one wave per row
    const int lane = threadIdx.x & 63;

    const float cnt  = counts[row];
    const float c    = cb[(size_t)row * DH + lane];
    const float mean = sums[(size_t)row * DH + lane] / fmaxf(cnt, 1.0f);

    float dot = mean * c;
    float nl  = mean * mean;
    float nh  = c * c;
#pragma unroll
    for (int off = 32; off; off >>= 1) {
        dot += __shfl_xor(dot, off, 64);
        nl  += __shfl_xor(nl,  off, 64);
        nh  += __shfl_xor(nh,  off, 64);
    }

    float cosv = dot / fmaxf(sqrtf(nl) * sqrtf(nh), 1e-8f);
    cosv = fminf(fmaxf(cosv, -0.9999999f), 0.9999999f);
    const float omega = acosf(cosv);
    const float so    = sinf(omega);
    // slerp(means, cb, val=0.99): (means*sin((1-val)*omega) + cb*sin(val*omega)) / so
    float outv = (mean * sinf(0.01f * omega) + c * sinf(0.99f * omega)) / so;

    // rms_norm over the row
    float ms = outv * outv;
#pragma unroll
    for (int off = 32; off; off >>= 1) ms += __shfl_xor(ms, off, 64);
    ms = ms * (1.0f / (float)DH) + 1.1920929e-07f;
    const float normed = outv / sqrtf(ms);

    cb_out[(size_t)row * DH + lane] = (cnt > 0.f) ? normed : c;
}

extern "C" void kernel_launch(void* const* d_in, const int* in_sizes, int n_in,
                              void* d_out, int out_size, void* d_ws, size_t ws_size,
                              hipStream_t stream) {
    const float* z  = (const float*)d_in[0];
    const float* cb = (const float*)d_in[1];
    float* out = (float*)d_out;
    float* ws  = (float*)d_ws;

    // zero the accumulator workspace (sums, counts, sse)
    hipMemsetAsync(d_ws, 0, (size_t)WS_FLOATS * sizeof(float), stream);

    dim3 gridA(NN / 256, HH);
    vq_assign_kernel<<<gridA, 256, 0, stream>>>(
        z, cb,
        out + OFF_ZQ, out + OFF_IDX,
        ws + WS_SUMS, ws + WS_COUNTS, ws + WS_SSE);

    dim3 gridB((HH * MM) / 4);
    vq_update_kernel<<<gridB, 256, 0, stream>>>(
        cb, ws + WS_SUMS, ws + WS_COUNTS, ws + WS_SSE,
        out + OFF_CB, out + OFF_LOSS);
}

// Round 5
// 769.952 us; speedup vs baseline: 1.2381x; 1.2381x over previous
//
#include <hip/hip_runtime.h>
#include <hip/hip_bf16.h>
#include <math.h>

// Problem constants (from reference setup_inputs)
#define BZ   8
#define DD   512
#define LL   2048
#define HH   8
#define MM   1024
#define DH   64
#define NN   (BZ * LL)               // 16384 rows per head
#define TOTAL_ELEMS (HH * NN * DH)   // 8388608

// d_out layout (floats): [z_q (8388608)] [vq_loss (1)] [indices (131072)] [codebooks (524288)]
#define OFF_ZQ   0
#define OFF_LOSS 8388608
#define OFF_IDX  8388609
#define OFF_CB   8519681

// d_ws layout (floats): [sums (524288)] [counts (8192)] [sse (1)]
#define WS_SUMS   0
#define WS_COUNTS 524288
#define WS_SSE    532480
#define WS_FLOATS 532481

#define TM             128   // codebook rows per LDS tile (32 KB)
#define ROWS_PER_BLOCK 128   // 256 threads, 2 threads per row

// R4 lesson: the SGPR-codebook design serializes on SMEM latency (64-SGPR row
// -> no room to prefetch row m+1 -> lgkmcnt(0) drain every m; only 2
// waves/SIMD to hide it -> ~470 stall cyc/m). This version: k-split-2 per row
// (32 zr floats/thread -> fits the RA's 64-VGPR budget naturally; 4
// waves/SIMD) + codebook tiles in LDS (ds_read_b128, 2 distinct addrs/wave =
// 2-way bank aliasing = free; LDS pipe overlaps VALU across waves).
__global__ __launch_bounds__(256)
__attribute__((amdgpu_waves_per_eu(4, 4)))
void vq_assign_kernel(
    const float* __restrict__ z,          // [B, D, L]
    const float* __restrict__ cb,         // [H, M, DH]
    float* __restrict__ zq_out,           // [B, D, L]
    float* __restrict__ idx_out,          // [B, H, L] as float
    float* __restrict__ sums,             // [H, M, DH]
    float* __restrict__ counts,           // [H, M]
    float* __restrict__ sse)              // [1]
{
    __shared__ float smem[TM * DH];       // 32 KB codebook tile

    const int t     = threadIdx.x;
    const int half  = t & 1;              // which 32-elem k-half this thread owns
    const int kbase = half * 32;
    const int n     = blockIdx.x * ROWS_PER_BLOCK + (t >> 1);
    const int h     = blockIdx.y;
    const int b     = n >> 11;            // n / LL
    const int l     = n & (LL - 1);       // n % LL

    // 32 z elements of this half-row. z_split[h,n,k] = z[b, h*64+k, l]
    const float* __restrict__ zp = z + ((size_t)(b * DD + h * DH + kbase) * LL + l);
    float zr[32];
#pragma unroll
    for (int j = 0; j < 32; ++j) zr[j] = zp[(size_t)j * LL];
#pragma unroll
    for (int j = 0; j < 32; ++j) asm volatile("" : "+v"(zr[j]));

    const float* __restrict__ cbh = cb + (size_t)h * MM * DH;

    float b1 = -1e30f, b2 = -1e30f;
    int i1 = 0, i2 = 0;

    for (int tile = 0; tile < MM / TM; ++tile) {
        __syncthreads();   // protect smem from previous tile's readers
        // stage TM codebook rows (8192 floats) as float4, coalesced
        const float4* __restrict__ src = (const float4*)(cbh + (size_t)tile * TM * DH);
#pragma unroll
        for (int i = 0; i < (TM * DH / 4) / 256; ++i)
            ((float4*)smem)[i * 256 + t] = src[i * 256 + t];
        __syncthreads();

#pragma unroll 1
        for (int mm = 0; mm < TM; ++mm) {
            const float4* __restrict__ c4 = (const float4*)(smem + mm * DH + kbase);
            float a0 = 0.f, a1 = 0.f, a2 = 0.f, a3 = 0.f;
#pragma unroll
            for (int j = 0; j < 8; ++j) {
                const float4 cv = c4[j];
                a0 = fmaf(zr[4 * j + 0], cv.x, a0);
                a1 = fmaf(zr[4 * j + 1], cv.y, a1);
                a2 = fmaf(zr[4 * j + 2], cv.z, a2);
                a3 = fmaf(zr[4 * j + 3], cv.w, a3);
            }
            float s = (a0 + a1) + (a2 + a3);
            s += __shfl_xor(s, 1, 64);         // combine the two k-halves
            const int m = tile * TM + mm;
            // Branchless top-2 (identical in both lanes of the pair).
            const bool gt1 = s > b1;
            const bool gt2 = s > b2;
            b2 = gt1 ? b1 : (gt2 ? s : b2);
            i2 = gt1 ? i1 : (gt2 ? m : i2);
            b1 = gt1 ? s : b1;
            i1 = gt1 ? m : i1;
        }
    }

    // fp64 rescreen of the two candidates (resolves fp32 near-ties exactly).
    const float* __restrict__ c1 = cbh + (size_t)i1 * DH + kbase;
    const float* __restrict__ c2 = cbh + (size_t)i2 * DH + kbase;
    double d1 = 0.0, d2 = 0.0;
#pragma unroll
    for (int j = 0; j < 32; ++j) {
        d1 = fma((double)zr[j], (double)c1[j], d1);
        d2 = fma((double)zr[j], (double)c2[j], d2);
    }
    d1 += __shfl_xor(d1, 1, 64);
    d2 += __shfl_xor(d2, 1, 64);
    const int best = (d2 > d1 || (d2 == d1 && i2 < i1)) ? i2 : i1;

    // Epilogue: quantized half-row, squared error, segment sums.
    const float* __restrict__ cq = cbh + (size_t)best * DH + kbase;
    float* __restrict__ zqp  = zq_out + ((size_t)(b * DD + h * DH + kbase) * LL + l);
    float* __restrict__ srow = sums + ((size_t)h * MM + best) * DH + kbase;
    float err = 0.f;
#pragma unroll
    for (int j = 0; j < 32; ++j) {
        const float q = cq[j];
        zqp[(size_t)j * LL] = q;
        const float dk = zr[j] - q;
        err = fmaf(dk, dk, err);
        atomicAdd(&srow[j], zr[j]);
    }
    if (half == 0) {
        atomicAdd(&counts[h * MM + best], 1.0f);
        idx_out[((size_t)b * HH + h) * LL + l] = (float)best;
    }
    // wave-level reduce of err (covers 32 rows x 64 k), one atomic per wave
#pragma unroll
    for (int off = 32; off; off >>= 1) err += __shfl_xor(err, off, 64);
    if ((t & 63) == 0) atomicAdd(sse, err);
}

__global__ __launch_bounds__(256) void vq_update_kernel(
    const float* __restrict__ cb,       // [H, M, DH]
    const float* __restrict__ sums,
    const float* __restrict__ counts,
    const float* __restrict__ sse,
    float* __restrict__ cb_out,         // [H, M, DH]
    float* __restrict__ loss_out)       // [1]
{
    if (blockIdx.x == 0 && threadIdx.x == 0) {
        loss_out[0] = 1.25f * sse[0] / (float)TOTAL_ELEMS;
    }
    const int row  = blockIdx.x * 4 + (threadIdx.x >> 6);   // (h*MM + m), one wave per row
    const int lane = threadIdx.x & 63;

    const float cnt  = counts[row];
    const float c    = cb[(size_t)row * DH + lane];
    const float mean = sums[(size_t)row * DH + lane] / fmaxf(cnt, 1.0f);

    float dot = mean * c;
    float nl  = mean * mean;
    float nh  = c * c;
#pragma unroll
    for (int off = 32; off; off >>= 1) {
        dot += __shfl_xor(dot, off, 64);
        nl  += __shfl_xor(nl,  off, 64);
        nh  += __shfl_xor(nh,  off, 64);
    }

    float cosv = dot / fmaxf(sqrtf(nl) * sqrtf(nh), 1e-8f);
    cosv = fminf(fmaxf(cosv, -0.9999999f), 0.9999999f);
    const float omega = acosf(cosv);
    const float so    = sinf(omega);
    // slerp(means, cb, val=0.99): (means*sin(0.01*omega) + cb*sin(0.99*omega)) / so
    float outv = (mean * sinf(0.01f * omega) + c * sinf(0.99f * omega)) / so;

    // rms_norm over the row
    float ms = outv * outv;
#pragma unroll
    for (int off = 32; off; off >>= 1) ms += __shfl_xor(ms, off, 64);
    ms = ms * (1.0f / (float)DH) + 1.1920929e-07f;
    const float normed = outv / sqrtf(ms);

    cb_out[(size_t)row * DH + lane] = (cnt > 0.f) ? normed : c;
}

extern "C" void kernel_launch(void* const* d_in, const int* in_sizes, int n_in,
                              void* d_out, int out_size, void* d_ws, size_t ws_size,
                              hipStream_t stream) {
    const float* z  = (const float*)d_in[0];
    const float* cb = (const float*)d_in[1];
    float* out = (float*)d_out;
    float* ws  = (float*)d_ws;

    // zero the accumulator workspace (sums, counts, sse)
    hipMemsetAsync(d_ws, 0, (size_t)WS_FLOATS * sizeof(float), stream);

    dim3 gridA(NN / ROWS_PER_BLOCK, HH);   // (128, 8), 1024 blocks, 4 waves/SIMD
    vq_assign_kernel<<<gridA, 256, 0, stream>>>(
        z, cb,
        out + OFF_ZQ, out + OFF_IDX,
        ws + WS_SUMS, ws + WS_COUNTS, ws + WS_SSE);

    dim3 gridB((HH * MM) / 4);
    vq_update_kernel<<<gridB, 256, 0, stream>>>(
        cb, ws + WS_SUMS, ws + WS_COUNTS, ws + WS_SSE,
        out + OFF_CB, out + OFF_LOSS);
}

// Round 6
// 604.645 us; speedup vs baseline: 1.5766x; 1.2734x over previous
//
#include <hip/hip_runtime.h>
#include <hip/hip_bf16.h>
#include <math.h>

// Problem constants
#define BZ   8
#define DD   512
#define LL   2048
#define HH   8
#define MM   1024
#define DH   64
#define NN   (BZ * LL)               // 16384 rows per head
#define TOTAL_ELEMS (HH * NN * DH)   // 8388608

// d_out layout (floats): [z_q (8388608)] [vq_loss (1)] [indices (131072)] [codebooks (524288)]
#define OFF_ZQ   0
#define OFF_LOSS 8388608
#define OFF_IDX  8388609
#define OFF_CB   8519681

// d_ws layout (floats): [sums (524288)] [counts (8192)] [sse (1)]
#define WS_SUMS   0
#define WS_COUNTS 524288
#define WS_SSE    532480
#define WS_FLOATS 532481

#define TM      64    // codebook rows per LDS tile
#define CB_PAD  72    // LDS row stride in shorts (16B-aligned writes, conflict-free frag reads)

typedef __attribute__((ext_vector_type(8))) short short8;
typedef __attribute__((ext_vector_type(4))) float float4v;

__device__ __forceinline__ unsigned short f2bf(float f) {
    unsigned int u = __builtin_bit_cast(unsigned int, f);
    u += 0x7FFFu + ((u >> 16) & 1u);          // RNE
    return (unsigned short)(u >> 16);
}
__device__ __forceinline__ float bf2f(unsigned short s) {
    unsigned int u = ((unsigned int)s) << 16;
    return __builtin_bit_cast(float, u);
}

// R5 lesson: the VALU scan was LDS-issue-bound (every lane broadcast-read the
// same codebook row: 8 ds_read_b128/wave/m * 16 waves/CU * 12cyc = 655us).
// MFMA amortizes: one ds_read_b128 feeds 8192 MACs. fp32 accuracy recovered
// via hi/lo bf16 split (3 MFMA passes, zl*cl term ~4e-6 dropped); exact fp64
// rescreen of the top-2 from global fp32 remains the final arbiter.
__global__ __launch_bounds__(256) void vq_assign_kernel(
    const float* __restrict__ z,          // [B, D, L]
    const float* __restrict__ cb,         // [H, M, DH]
    float* __restrict__ zq_out,           // [B, D, L]
    float* __restrict__ idx_out,          // [B, H, L] as float
    float* __restrict__ sums,             // [H, M, DH]
    float* __restrict__ counts,           // [H, M]
    float* __restrict__ sse)              // [1]
{
    __shared__ short cb_hi_lds[TM * CB_PAD];   // 9216 B
    __shared__ short cb_lo_lds[TM * CB_PAD];   // 9216 B

    const int t    = threadIdx.x;
    const int h    = blockIdx.y;
    const int lane = t & 63;
    const int g    = lane >> 4;          // quad 0..3
    const int nloc = lane & 15;
    const int w    = t >> 6;             // wave 0..3

    // This lane's z row (16 rows per wave, 64 per block)
    const int r = blockIdx.x * 64 + w * 16 + nloc;   // row in [0, NN)
    const int b = r >> 11;
    const int l = r & (LL - 1);
    const float* __restrict__ zbase = z + ((size_t)(b * DD + h * DH) * LL + l);

    // Load the 16 z values this lane owns in the B-fragment layout:
    // k = khalf*32 + g*8 + j   (j=0..7)
    float zv[16];
#pragma unroll
    for (int j = 0; j < 8; ++j) zv[j]     = zbase[(size_t)(g * 8 + j) * LL];
#pragma unroll
    for (int j = 0; j < 8; ++j) zv[8 + j] = zbase[(size_t)(32 + g * 8 + j) * LL];

    // hi/lo bf16 split, packed into MFMA B-operand fragments
    short bh[16], bl[16];
#pragma unroll
    for (int j = 0; j < 16; ++j) {
        unsigned short hi = f2bf(zv[j]);
        bh[j] = (short)hi;
        bl[j] = (short)f2bf(zv[j] - bf2f(hi));
    }
    short8 Bh0 = *(short8*)&bh[0], Bh1 = *(short8*)&bh[8];
    short8 Bl0 = *(short8*)&bl[0], Bl1 = *(short8*)&bl[8];

    const float* __restrict__ cbh = cb + (size_t)h * MM * DH;

    // staging decomposition: thread -> (row rr, quarter q) of the 64x64 tile
    const int rr = t >> 2;
    const int qq = t & 3;

    float b1 = -1e30f, b2 = -1e30f;
    int   i1 = 0,      i2 = 0;

    for (int mt = 0; mt < MM / TM; ++mt) {
        __syncthreads();
        // Stage 64 codebook rows: fp32 global -> bf16 hi/lo in LDS.
        {
            const float4* __restrict__ s4 =
                (const float4*)(cbh + (size_t)(mt * TM + rr) * DH + qq * 16);
            float fa[16];
            *(float4*)&fa[0]  = s4[0];
            *(float4*)&fa[4]  = s4[1];
            *(float4*)&fa[8]  = s4[2];
            *(float4*)&fa[12] = s4[3];
            short hs[16], ls[16];
#pragma unroll
            for (int j = 0; j < 16; ++j) {
                unsigned short hi = f2bf(fa[j]);
                hs[j] = (short)hi;
                ls[j] = (short)f2bf(fa[j] - bf2f(hi));
            }
            const int off = rr * CB_PAD + qq * 16;
            *(short8*)&cb_hi_lds[off]     = *(short8*)&hs[0];
            *(short8*)&cb_hi_lds[off + 8] = *(short8*)&hs[8];
            *(short8*)&cb_lo_lds[off]     = *(short8*)&ls[0];
            *(short8*)&cb_lo_lds[off + 8] = *(short8*)&ls[8];
        }
        __syncthreads();

#pragma unroll
        for (int s = 0; s < 4; ++s) {
            // A-fragments (codebook): A[m=lane&15][k=g*8+j], khalf 0/1, hi/lo
            const int aoff = (s * 16 + nloc) * CB_PAD + g * 8;
            short8 Ah0 = *(short8*)&cb_hi_lds[aoff];
            short8 Ah1 = *(short8*)&cb_hi_lds[aoff + 32];
            short8 Al0 = *(short8*)&cb_lo_lds[aoff];
            short8 Al1 = *(short8*)&cb_lo_lds[aoff + 32];

            float4v acc = {0.f, 0.f, 0.f, 0.f};
            acc = __builtin_amdgcn_mfma_f32_16x16x32_bf16(Ah0, Bh0, acc, 0, 0, 0);
            acc = __builtin_amdgcn_mfma_f32_16x16x32_bf16(Ah1, Bh1, acc, 0, 0, 0);
            acc = __builtin_amdgcn_mfma_f32_16x16x32_bf16(Ah0, Bl0, acc, 0, 0, 0);
            acc = __builtin_amdgcn_mfma_f32_16x16x32_bf16(Ah1, Bl1, acc, 0, 0, 0);
            acc = __builtin_amdgcn_mfma_f32_16x16x32_bf16(Al0, Bh0, acc, 0, 0, 0);
            acc = __builtin_amdgcn_mfma_f32_16x16x32_bf16(Al1, Bh1, acc, 0, 0, 0);

            // C/D layout: col = lane&15 (= n), row = g*4 + reg (= m within subtile)
            const int mbase = mt * TM + s * 16 + g * 4;
#pragma unroll
            for (int reg = 0; reg < 4; ++reg) {
                const float v = acc[reg];
                const int   m = mbase + reg;
                const bool gt1 = v > b1;
                const bool gt2 = v > b2;
                b2 = gt1 ? b1 : (gt2 ? v : b2);
                i2 = gt1 ? i1 : (gt2 ? m : i2);
                b1 = gt1 ? v : b1;
                i1 = gt1 ? m : i1;
            }
        }
    }

    // Merge top-2 across the 4 quads holding the same n (lanes l, l^16, l^32).
#pragma unroll
    for (int off = 16; off <= 32; off <<= 1) {
        float ob1 = __shfl_xor(b1, off, 64);
        int   oi1 = __shfl_xor(i1, off, 64);
        float ob2 = __shfl_xor(b2, off, 64);
        int   oi2 = __shfl_xor(i2, off, 64);
        const bool agt = (b1 > ob1) || (b1 == ob1 && i1 < oi1);
        const float w1  = agt ? b1 : ob1;  const int wi1 = agt ? i1 : oi1;
        const float l1  = agt ? ob1 : b1;  const int li1 = agt ? oi1 : i1;
        const float w2  = agt ? b2 : ob2;  const int wi2 = agt ? i2 : oi2;
        const bool sgt = (l1 > w2) || (l1 == w2 && li1 < wi2);
        b1 = w1;  i1 = wi1;
        b2 = sgt ? l1 : w2;  i2 = sgt ? li1 : wi2;
    }

    // Exact fp64 rescreen of the two candidates from global fp32 memory.
    // Lane (g, n) covers k = g*16 .. g*16+15 of row n.
    const int kk0 = g * 16;
    const float* __restrict__ zxp = z + ((size_t)(b * DD + h * DH + kk0) * LL + l);
    float zx[16];
#pragma unroll
    for (int j = 0; j < 16; ++j) zx[j] = zxp[(size_t)j * LL];

    const float* __restrict__ c1 = cbh + (size_t)i1 * DH + kk0;
    const float* __restrict__ c2 = cbh + (size_t)i2 * DH + kk0;
    double d1 = 0.0, d2 = 0.0;
#pragma unroll
    for (int j = 0; j < 16; ++j) {
        d1 = fma((double)zx[j], (double)c1[j], d1);
        d2 = fma((double)zx[j], (double)c2[j], d2);
    }
    d1 += __shfl_xor(d1, 16, 64);  d1 += __shfl_xor(d1, 32, 64);
    d2 += __shfl_xor(d2, 16, 64);  d2 += __shfl_xor(d2, 32, 64);
    const int best = (d2 > d1 || (d2 == d1 && i2 < i1)) ? i2 : i1;

    // Epilogue: quantized row chunk, squared error, segment sums.
    const float* __restrict__ cq  = cbh + (size_t)best * DH + kk0;
    float* __restrict__ zqp  = zq_out + ((size_t)(b * DD + h * DH + kk0) * LL + l);
    float* __restrict__ srow = sums + ((size_t)h * MM + best) * DH + kk0;
    float err = 0.f;
#pragma unroll
    for (int j = 0; j < 16; ++j) {
        const float q = cq[j];
        zqp[(size_t)j * LL] = q;
        const float dk = zx[j] - q;
        err = fmaf(dk, dk, err);
        atomicAdd(&srow[j], zx[j]);
    }
    if (g == 0) {
        atomicAdd(&counts[h * MM + best], 1.0f);
        idx_out[((size_t)b * HH + h) * LL + l] = (float)best;
    }
#pragma unroll
    for (int off = 32; off; off >>= 1) err += __shfl_xor(err, off, 64);
    if (lane == 0) atomicAdd(sse, err);
}

__global__ __launch_bounds__(256) void vq_update_kernel(
    const float* __restrict__ cb,       // [H, M, DH]
    const float* __restrict__ sums,
    const float* __restrict__ counts,
    const float* __restrict__ sse,
    float* __restrict__ cb_out,         // [H, M, DH]
    float* __restrict__ loss_out)       // [1]
{
    if (blockIdx.x == 0 && threadIdx.x == 0) {
        loss_out[0] = 1.25f * sse[0] / (float)TOTAL_ELEMS;
    }
    const int row  = blockIdx.x * 4 + (threadIdx.x >> 6);   // (h*MM + m)
    const int lane = threadIdx.x & 63;

    const float cnt  = counts[row];
    const float c    = cb[(size_t)row * DH + lane];
    const float mean = sums[(size_t)row * DH + lane] / fmaxf(cnt, 1.0f);

    float dot = mean * c;
    float nl  = mean * mean;
    float nh  = c * c;
#pragma unroll
    for (int off = 32; off; off >>= 1) {
        dot += __shfl_xor(dot, off, 64);
        nl  += __shfl_xor(nl,  off, 64);
        nh  += __shfl_xor(nh,  off, 64);
    }

    float cosv = dot / fmaxf(sqrtf(nl) * sqrtf(nh), 1e-8f);
    cosv = fminf(fmaxf(cosv, -0.9999999f), 0.9999999f);
    const float omega = acosf(cosv);
    const float so    = sinf(omega);
    float outv = (mean * sinf(0.01f * omega) + c * sinf(0.99f * omega)) / so;

    float ms = outv * outv;
#pragma unroll
    for (int off = 32; off; off >>= 1) ms += __shfl_xor(ms, off, 64);
    ms = ms * (1.0f / (float)DH) + 1.1920929e-07f;
    const float normed = outv / sqrtf(ms);

    cb_out[(size_t)row * DH + lane] = (cnt > 0.f) ? normed : c;
}

extern "C" void kernel_launch(void* const* d_in, const int* in_sizes, int n_in,
                              void* d_out, int out_size, void* d_ws, size_t ws_size,
                              hipStream_t stream) {
    const float* z  = (const float*)d_in[0];
    const float* cb = (const float*)d_in[1];
    float* out = (float*)d_out;
    float* ws  = (float*)d_ws;

    hipMemsetAsync(d_ws, 0, (size_t)WS_FLOATS * sizeof(float), stream);

    dim3 gridA(NN / 64, HH);   // (256, 8) = 2048 blocks, 4 waves each
    vq_assign_kernel<<<gridA, 256, 0, stream>>>(
        z, cb,
        out + OFF_ZQ, out + OFF_IDX,
        ws + WS_SUMS, ws + WS_COUNTS, ws + WS_SSE);

    dim3 gridB((HH * MM) / 4);
    vq_update_kernel<<<gridB, 256, 0, stream>>>(
        cb, ws + WS_SUMS, ws + WS_COUNTS, ws + WS_SSE,
        out + OFF_CB, out + OFF_LOSS);
}

// Round 7
// 383.172 us; speedup vs baseline: 2.4878x; 1.5780x over previous
//
#include <hip/hip_runtime.h>
#include <hip/hip_bf16.h>
#include <math.h>

// Problem constants
#define BZ   8
#define DD   512
#define LL   2048
#define HH   8
#define MM   1024
#define DH   64
#define NN   (BZ * LL)               // 16384 rows per head
#define TOTAL_ELEMS (HH * NN * DH)   // 8388608

// d_out layout (floats): [z_q (8388608)] [vq_loss (1)] [indices (131072)] [codebooks (524288)]
#define OFF_ZQ   0
#define OFF_LOSS 8388608
#define OFF_IDX  8388609
#define OFF_CB   8519681

// d_ws layout: floats [sums (524288)] [counts (8192)] [sse (1)] | 16B-aligned:
// bf16-hi plane (524288 shorts) | bf16-lo plane (524288 shorts). ~4.2 MB total.
#define WS_SUMS        0
#define WS_COUNTS      524288
#define WS_SSE         532480
#define WS_ZERO_FLOATS 532481
#define WS_PLANES_BYTE 2129936   // 532484 floats, 16B-aligned

typedef __attribute__((ext_vector_type(8))) short short8;
typedef __attribute__((ext_vector_type(4))) float float4v;

__device__ __forceinline__ unsigned short f2bf(float f) {
    unsigned int u = __builtin_bit_cast(unsigned int, f);
    u += 0x7FFFu + ((u >> 16) & 1u);          // RNE
    return (unsigned short)(u >> 16);
}
__device__ __forceinline__ float bf2f(unsigned short s) {
    unsigned int u = ((unsigned int)s) << 16;
    return __builtin_bit_cast(float, u);
}

__device__ __forceinline__ void gload16(const short* g, short* l) {
    __builtin_amdgcn_global_load_lds(
        (const __attribute__((address_space(1))) unsigned int*)g,
        (__attribute__((address_space(3))) unsigned int*)l, 16, 0, 0);
}

// Prep: fp32 codebook -> bf16 hi/lo planes, 16B chunks XOR-swizzled within each
// 128B row (chunk c stored at c^(row&7)) so unpadded LDS tiles read conflict-free.
__global__ __launch_bounds__(256) void cvt_cb_kernel(
    const float* __restrict__ cb, short* __restrict__ hip_, short* __restrict__ lop_)
{
    const int tid = blockIdx.x * 256 + threadIdx.x;   // 65536 threads, one 8-elem chunk each
    const int c   = tid & 7;
    const int row = tid >> 3;                          // h*MM + m, 0..8191
    const float* __restrict__ src = cb + (size_t)row * DH + c * 8;
    short hs[8], ls[8];
#pragma unroll
    for (int j = 0; j < 8; ++j) {
        const float f = src[j];
        const unsigned short hv = f2bf(f);
        hs[j] = (short)hv;
        ls[j] = (short)f2bf(f - bf2f(hv));
    }
    const int dst = row * DH + ((c ^ (row & 7)) * 8);
    *(short8*)&hip_[dst] = *(short8*)hs;
    *(short8*)&lop_[dst] = *(short8*)ls;
}

// R6 lesson: scan was latency-bound (all pipes <15%): per tile, global load ->
// fp32->bf16 convert -> ds_write -> barrier was a serialized chain repeated 16x.
// Now: conversion hoisted to cvt_cb_kernel (done once, not 2048x), staging is
// global_load_lds (async DMA, no VGPR/VALU), double-buffered with ONE barrier
// per tile: the vmcnt(0) the compiler emits at each __syncthreads waits exactly
// for the loads we're about to consume; next tile's loads fly during compute.
__global__ __launch_bounds__(256) void vq_assign_kernel(
    const float* __restrict__ z,          // [B, D, L]
    const float* __restrict__ cb,         // [H, M, DH] fp32 (rescreen/epilogue)
    const short* __restrict__ cb_hi,      // [H, M, DH] bf16 hi, swizzled
    const short* __restrict__ cb_lo,      // [H, M, DH] bf16 lo, swizzled
    float* __restrict__ zq_out,
    float* __restrict__ idx_out,
    float* __restrict__ sums,
    float* __restrict__ counts,
    float* __restrict__ sse)
{
    __shared__ __align__(16) short hi_lds[2][64 * DH];   // 2 x 8 KB
    __shared__ __align__(16) short lo_lds[2][64 * DH];   // 2 x 8 KB

    const int t    = threadIdx.x;
    const int h    = blockIdx.y;
    const int lane = t & 63;
    const int g    = lane >> 4;          // quad 0..3
    const int nloc = lane & 15;
    const int w    = t >> 6;             // wave 0..3

    // This lane's z row (16 rows per wave, 64 per block); 4 quads share a row.
    const int r = blockIdx.x * 64 + w * 16 + nloc;
    const int b = r >> 11;
    const int l = r & (LL - 1);
    const float* __restrict__ zbase = z + ((size_t)(b * DD + h * DH) * LL + l);

    // B-fragment z values: zv[j] <-> k=g*8+j, zv[8+j] <-> k=32+g*8+j.
    float zv[16];
#pragma unroll
    for (int j = 0; j < 8; ++j) zv[j]     = zbase[(size_t)(g * 8 + j) * LL];
#pragma unroll
    for (int j = 0; j < 8; ++j) zv[8 + j] = zbase[(size_t)(32 + g * 8 + j) * LL];

    short bh[16], bl[16];
#pragma unroll
    for (int j = 0; j < 16; ++j) {
        const unsigned short hv = f2bf(zv[j]);
        bh[j] = (short)hv;
        bl[j] = (short)f2bf(zv[j] - bf2f(hv));
    }
    const short8 Bh0 = *(short8*)&bh[0], Bh1 = *(short8*)&bh[8];
    const short8 Bl0 = *(short8*)&bl[0], Bl1 = *(short8*)&bl[8];

    const short* __restrict__ gh = cb_hi + (size_t)h * MM * DH;
    const short* __restrict__ gl = cb_lo + (size_t)h * MM * DH;

    // Stage one 64-row tile (8 KB hi + 8 KB lo) via async global->LDS DMA.
    auto stage = [&](int mt, int buf) {
        const short* sh = gh + (size_t)mt * 64 * DH;
        const short* sl = gl + (size_t)mt * 64 * DH;
        gload16(sh + t * 8,        &hi_lds[buf][t * 8]);
        gload16(sh + 2048 + t * 8, &hi_lds[buf][2048 + t * 8]);
        gload16(sl + t * 8,        &lo_lds[buf][t * 8]);
        gload16(sl + 2048 + t * 8, &lo_lds[buf][2048 + t * 8]);
    };

    stage(0, 0);

    float b1 = -1e30f, b2 = -1e30f;
    int   i1 = 0,      i2 = 0;
    const int sw8 = nloc & 7;

    for (int mt = 0; mt < MM / 64; ++mt) {
        __syncthreads();                       // vmcnt(0) waits tile mt's DMA; syncs buffers
        if (mt + 1 < MM / 64) stage(mt + 1, (mt + 1) & 1);
        const int buf = mt & 1;

#pragma unroll
        for (int s = 0; s < 4; ++s) {
            const short* hrow = &hi_lds[buf][(s * 16 + nloc) * DH];
            const short* lrow = &lo_lds[buf][(s * 16 + nloc) * DH];
            // swizzled chunks: khalf0 chunk g, khalf1 chunk g+4, XOR row&7
            const short8 Ah0 = *(const short8*)&hrow[((g)     ^ sw8) * 8];
            const short8 Ah1 = *(const short8*)&hrow[((g + 4) ^ sw8) * 8];
            const short8 Al0 = *(const short8*)&lrow[((g)     ^ sw8) * 8];
            const short8 Al1 = *(const short8*)&lrow[((g + 4) ^ sw8) * 8];

            float4v acc = {0.f, 0.f, 0.f, 0.f};
            acc = __builtin_amdgcn_mfma_f32_16x16x32_bf16(Ah0, Bh0, acc, 0, 0, 0);
            acc = __builtin_amdgcn_mfma_f32_16x16x32_bf16(Ah1, Bh1, acc, 0, 0, 0);
            acc = __builtin_amdgcn_mfma_f32_16x16x32_bf16(Ah0, Bl0, acc, 0, 0, 0);
            acc = __builtin_amdgcn_mfma_f32_16x16x32_bf16(Ah1, Bl1, acc, 0, 0, 0);
            acc = __builtin_amdgcn_mfma_f32_16x16x32_bf16(Al0, Bh0, acc, 0, 0, 0);
            acc = __builtin_amdgcn_mfma_f32_16x16x32_bf16(Al1, Bh1, acc, 0, 0, 0);

            const int mbase = mt * 64 + s * 16 + g * 4;
#pragma unroll
            for (int reg = 0; reg < 4; ++reg) {
                const float v = acc[reg];
                const int   m = mbase + reg;
                const bool gt1 = v > b1;
                const bool gt2 = v > b2;
                b2 = gt1 ? b1 : (gt2 ? v : b2);
                i2 = gt1 ? i1 : (gt2 ? m : i2);
                b1 = gt1 ? v : b1;
                i1 = gt1 ? m : i1;
            }
        }
    }

    // Merge top-2 across the 4 quads holding the same row.
#pragma unroll
    for (int off = 16; off <= 32; off <<= 1) {
        float ob1 = __shfl_xor(b1, off, 64);
        int   oi1 = __shfl_xor(i1, off, 64);
        float ob2 = __shfl_xor(b2, off, 64);
        int   oi2 = __shfl_xor(i2, off, 64);
        const bool agt = (b1 > ob1) || (b1 == ob1 && i1 < oi1);
        const float w1  = agt ? b1 : ob1;  const int wi1 = agt ? i1 : oi1;
        const float l1  = agt ? ob1 : b1;  const int li1 = agt ? oi1 : i1;
        const float w2  = agt ? b2 : ob2;  const int wi2 = agt ? i2 : oi2;
        const bool sgt = (l1 > w2) || (l1 == w2 && li1 < wi2);
        b1 = w1;  i1 = wi1;
        b2 = sgt ? l1 : w2;  i2 = sgt ? li1 : wi2;
    }

    // Exact fp64 rescreen of the two candidates (global fp32), reusing zv.
    const float* __restrict__ cbh = cb + (size_t)h * MM * DH;
    const float* __restrict__ c1  = cbh + (size_t)i1 * DH;
    const float* __restrict__ c2  = cbh + (size_t)i2 * DH;
    double d1 = 0.0, d2 = 0.0;
#pragma unroll
    for (int j = 0; j < 8; ++j) {
        const int k0 = g * 8 + j, k1 = 32 + g * 8 + j;
        d1 = fma((double)zv[j],     (double)c1[k0], d1);
        d1 = fma((double)zv[8 + j], (double)c1[k1], d1);
        d2 = fma((double)zv[j],     (double)c2[k0], d2);
        d2 = fma((double)zv[8 + j], (double)c2[k1], d2);
    }
    d1 += __shfl_xor(d1, 16, 64);  d1 += __shfl_xor(d1, 32, 64);
    d2 += __shfl_xor(d2, 16, 64);  d2 += __shfl_xor(d2, 32, 64);
    const int best = (d2 > d1 || (d2 == d1 && i2 < i1)) ? i2 : i1;

    // Epilogue: quantized row, squared error, segment sums (k-partitioned per quad).
    const float* __restrict__ cq  = cbh + (size_t)best * DH;
    float* __restrict__ zqp  = zq_out + ((size_t)(b * DD + h * DH) * LL + l);
    float* __restrict__ srow = sums + ((size_t)h * MM + best) * DH;
    float err = 0.f;
#pragma unroll
    for (int j = 0; j < 8; ++j) {
        const int k0 = g * 8 + j, k1 = 32 + g * 8 + j;
        const float q0 = cq[k0], q1 = cq[k1];
        zqp[(size_t)k0 * LL] = q0;
        zqp[(size_t)k1 * LL] = q1;
        const float e0 = zv[j] - q0, e1 = zv[8 + j] - q1;
        err = fmaf(e0, e0, err);
        err = fmaf(e1, e1, err);
        atomicAdd(&srow[k0], zv[j]);
        atomicAdd(&srow[k1], zv[8 + j]);
    }
    if (g == 0) {
        atomicAdd(&counts[h * MM + best], 1.0f);
        idx_out[((size_t)b * HH + h) * LL + l] = (float)best;
    }
#pragma unroll
    for (int off = 32; off; off >>= 1) err += __shfl_xor(err, off, 64);
    if (lane == 0) atomicAdd(sse, err);
}

__global__ __launch_bounds__(256) void vq_update_kernel(
    const float* __restrict__ cb,
    const float* __restrict__ sums,
    const float* __restrict__ counts,
    const float* __restrict__ sse,
    float* __restrict__ cb_out,
    float* __restrict__ loss_out)
{
    if (blockIdx.x == 0 && threadIdx.x == 0) {
        loss_out[0] = 1.25f * sse[0] / (float)TOTAL_ELEMS;
    }
    const int row  = blockIdx.x * 4 + (threadIdx.x >> 6);   // (h*MM + m)
    const int lane = threadIdx.x & 63;

    const float cnt  = counts[row];
    const float c    = cb[(size_t)row * DH + lane];
    const float mean = sums[(size_t)row * DH + lane] / fmaxf(cnt, 1.0f);

    float dot = mean * c;
    float nl  = mean * mean;
    float nh  = c * c;
#pragma unroll
    for (int off = 32; off; off >>= 1) {
        dot += __shfl_xor(dot, off, 64);
        nl  += __shfl_xor(nl,  off, 64);
        nh  += __shfl_xor(nh,  off, 64);
    }

    float cosv = dot / fmaxf(sqrtf(nl) * sqrtf(nh), 1e-8f);
    cosv = fminf(fmaxf(cosv, -0.9999999f), 0.9999999f);
    const float omega = acosf(cosv);
    const float so    = sinf(omega);
    float outv = (mean * sinf(0.01f * omega) + c * sinf(0.99f * omega)) / so;

    float ms = outv * outv;
#pragma unroll
    for (int off = 32; off; off >>= 1) ms += __shfl_xor(ms, off, 64);
    ms = ms * (1.0f / (float)DH) + 1.1920929e-07f;
    const float normed = outv / sqrtf(ms);

    cb_out[(size_t)row * DH + lane] = (cnt > 0.f) ? normed : c;
}

extern "C" void kernel_launch(void* const* d_in, const int* in_sizes, int n_in,
                              void* d_out, int out_size, void* d_ws, size_t ws_size,
                              hipStream_t stream) {
    const float* z  = (const float*)d_in[0];
    const float* cb = (const float*)d_in[1];
    float* out = (float*)d_out;
    float* ws  = (float*)d_ws;
    short* cb_hi = (short*)((char*)d_ws + WS_PLANES_BYTE);
    short* cb_lo = cb_hi + (size_t)HH * MM * DH;

    hipMemsetAsync(d_ws, 0, (size_t)WS_ZERO_FLOATS * sizeof(float), stream);

    cvt_cb_kernel<<<(HH * MM * DH / 8) / 256, 256, 0, stream>>>(cb, cb_hi, cb_lo);

    dim3 gridA(NN / 64, HH);   // (256, 8) = 2048 blocks, 4 waves each
    vq_assign_kernel<<<gridA, 256, 0, stream>>>(
        z, cb, cb_hi, cb_lo,
        out + OFF_ZQ, out + OFF_IDX,
        ws + WS_SUMS, ws + WS_COUNTS, ws + WS_SSE);

    dim3 gridB((HH * MM) / 4);
    vq_update_kernel<<<gridB, 256, 0, stream>>>(
        cb, ws + WS_SUMS, ws + WS_COUNTS, ws + WS_SSE,
        out + OFF_CB, out + OFF_LOSS);
}

// Round 8
// 285.886 us; speedup vs baseline: 3.3344x; 1.3403x over previous
//
#include <hip/hip_runtime.h>
#include <hip/hip_bf16.h>
#include <math.h>

// Problem constants
#define BZ   8
#define DD   512
#define LL   2048
#define HH   8
#define MM   1024
#define DH   64
#define NN   (BZ * LL)               // 16384 rows per head
#define TOTAL_ELEMS (HH * NN * DH)   // 8388608

// d_out layout (floats): [z_q (8388608)] [vq_loss (1)] [indices (131072)] [codebooks (524288)]
#define OFF_ZQ   0
#define OFF_LOSS 8388608
#define OFF_IDX  8388609
#define OFF_CB   8519681

// d_ws layout: [sse (1 float) pad to 64B] | bf16-hi plane (524288 shorts) | bf16-lo plane.
#define WS_PLANES_BYTE 64

typedef __attribute__((ext_vector_type(8))) short short8;
typedef __attribute__((ext_vector_type(4))) float float4v;

__device__ __forceinline__ unsigned short f2bf(float f) {
    unsigned int u = __builtin_bit_cast(unsigned int, f);
    u += 0x7FFFu + ((u >> 16) & 1u);          // RNE
    return (unsigned short)(u >> 16);
}
__device__ __forceinline__ float bf2f(unsigned short s) {
    unsigned int u = ((unsigned int)s) << 16;
    return __builtin_bit_cast(float, u);
}

__device__ __forceinline__ void gload16(const short* g, short* l) {
    __builtin_amdgcn_global_load_lds(
        (const __attribute__((address_space(1))) unsigned int*)g,
        (__attribute__((address_space(3))) unsigned int*)l, 16, 0, 0);
}

// Prep: fp32 codebook -> bf16 hi/lo planes, 16B chunks XOR-swizzled within each
// 128B row (chunk c stored at c^(row&7)) so unpadded LDS tiles read conflict-free.
__global__ __launch_bounds__(256) void cvt_cb_kernel(
    const float* __restrict__ cb, short* __restrict__ hip_, short* __restrict__ lop_)
{
    const int tid = blockIdx.x * 256 + threadIdx.x;
    const int c   = tid & 7;
    const int row = tid >> 3;                          // h*MM + m
    const float* __restrict__ src = cb + (size_t)row * DH + c * 8;
    short hs[8], ls[8];
#pragma unroll
    for (int j = 0; j < 8; ++j) {
        const float f = src[j];
        const unsigned short hv = f2bf(f);
        hs[j] = (short)hv;
        ls[j] = (short)f2bf(f - bf2f(hv));
    }
    const int dst = row * DH + ((c ^ (row & 7)) * 8);
    *(short8*)&hip_[dst] = *(short8*)hs;
    *(short8*)&lop_[dst] = *(short8*)ls;
}

// R7 lesson: WRITE_SIZE 300MB = 268MB of segment-sum atomic write-through.
// Segment sums moved to vq_update_kernel (idx-scan + gather). Kernel A now:
// scan (MFMA, dbuf DMA staging) + rescreen + zq/idx stores only.
// 512-thread blocks: 8 waves share each 32KB tile -> staged bytes per row halve.
__global__ __launch_bounds__(512) void vq_assign_kernel(
    const float* __restrict__ z,          // [B, D, L]
    const float* __restrict__ cb,         // [H, M, DH] fp32 (rescreen/epilogue)
    const short* __restrict__ cb_hi,      // bf16 hi, swizzled
    const short* __restrict__ cb_lo,      // bf16 lo, swizzled
    float* __restrict__ zq_out,
    float* __restrict__ idx_out,
    float* __restrict__ sse)
{
    __shared__ __align__(16) short hi_lds[2][64 * DH];   // 2 x 8 KB
    __shared__ __align__(16) short lo_lds[2][64 * DH];   // 2 x 8 KB

    const int t    = threadIdx.x;
    const int h    = blockIdx.y;
    const int lane = t & 63;
    const int g    = lane >> 4;          // quad 0..3
    const int nloc = lane & 15;
    const int w    = t >> 6;             // wave 0..7

    // This lane's z row (16 rows per wave, 128 per block); 4 quads share a row.
    const int r = blockIdx.x * 128 + w * 16 + nloc;
    const int b = r >> 11;
    const int l = r & (LL - 1);
    const float* __restrict__ zbase = z + ((size_t)(b * DD + h * DH) * LL + l);

    // B-fragment z values: zv[j] <-> k=g*8+j, zv[8+j] <-> k=32+g*8+j.
    float zv[16];
#pragma unroll
    for (int j = 0; j < 8; ++j) zv[j]     = zbase[(size_t)(g * 8 + j) * LL];
#pragma unroll
    for (int j = 0; j < 8; ++j) zv[8 + j] = zbase[(size_t)(32 + g * 8 + j) * LL];

    short bh[16], bl[16];
#pragma unroll
    for (int j = 0; j < 16; ++j) {
        const unsigned short hv = f2bf(zv[j]);
        bh[j] = (short)hv;
        bl[j] = (short)f2bf(zv[j] - bf2f(hv));
    }
    const short8 Bh0 = *(short8*)&bh[0], Bh1 = *(short8*)&bh[8];
    const short8 Bl0 = *(short8*)&bl[0], Bl1 = *(short8*)&bl[8];

    const short* __restrict__ gh = cb_hi + (size_t)h * MM * DH;
    const short* __restrict__ gl = cb_lo + (size_t)h * MM * DH;

    // Stage one 64-row tile (8 KB hi + 8 KB lo): 512 threads x 16B each plane.
    auto stage = [&](int mt, int buf) {
        const short* sh = gh + (size_t)mt * 64 * DH;
        const short* sl = gl + (size_t)mt * 64 * DH;
        gload16(sh + t * 8, &hi_lds[buf][t * 8]);
        gload16(sl + t * 8, &lo_lds[buf][t * 8]);
    };

    stage(0, 0);

    float b1 = -1e30f, b2 = -1e30f;
    int   i1 = 0,      i2 = 0;
    const int sw8 = nloc & 7;

    for (int mt = 0; mt < MM / 64; ++mt) {
        __syncthreads();                       // vmcnt(0) drains exactly tile mt's DMA
        if (mt + 1 < MM / 64) stage(mt + 1, (mt + 1) & 1);
        const int buf = mt & 1;

#pragma unroll
        for (int s = 0; s < 4; ++s) {
            const short* hrow = &hi_lds[buf][(s * 16 + nloc) * DH];
            const short* lrow = &lo_lds[buf][(s * 16 + nloc) * DH];
            const short8 Ah0 = *(const short8*)&hrow[((g)     ^ sw8) * 8];
            const short8 Ah1 = *(const short8*)&hrow[((g + 4) ^ sw8) * 8];
            const short8 Al0 = *(const short8*)&lrow[((g)     ^ sw8) * 8];
            const short8 Al1 = *(const short8*)&lrow[((g + 4) ^ sw8) * 8];

            float4v acc = {0.f, 0.f, 0.f, 0.f};
            acc = __builtin_amdgcn_mfma_f32_16x16x32_bf16(Ah0, Bh0, acc, 0, 0, 0);
            acc = __builtin_amdgcn_mfma_f32_16x16x32_bf16(Ah1, Bh1, acc, 0, 0, 0);
            acc = __builtin_amdgcn_mfma_f32_16x16x32_bf16(Ah0, Bl0, acc, 0, 0, 0);
            acc = __builtin_amdgcn_mfma_f32_16x16x32_bf16(Ah1, Bl1, acc, 0, 0, 0);
            acc = __builtin_amdgcn_mfma_f32_16x16x32_bf16(Al0, Bh0, acc, 0, 0, 0);
            acc = __builtin_amdgcn_mfma_f32_16x16x32_bf16(Al1, Bh1, acc, 0, 0, 0);

            const int mbase = mt * 64 + s * 16 + g * 4;
#pragma unroll
            for (int reg = 0; reg < 4; ++reg) {
                const float v = acc[reg];
                const int   m = mbase + reg;
                const bool gt1 = v > b1;
                const bool gt2 = v > b2;
                b2 = gt1 ? b1 : (gt2 ? v : b2);
                i2 = gt1 ? i1 : (gt2 ? m : i2);
                b1 = gt1 ? v : b1;
                i1 = gt1 ? m : i1;
            }
        }
    }

    // Merge top-2 across the 4 quads holding the same row.
#pragma unroll
    for (int off = 16; off <= 32; off <<= 1) {
        float ob1 = __shfl_xor(b1, off, 64);
        int   oi1 = __shfl_xor(i1, off, 64);
        float ob2 = __shfl_xor(b2, off, 64);
        int   oi2 = __shfl_xor(i2, off, 64);
        const bool agt = (b1 > ob1) || (b1 == ob1 && i1 < oi1);
        const float w1  = agt ? b1 : ob1;  const int wi1 = agt ? i1 : oi1;
        const float l1  = agt ? ob1 : b1;  const int li1 = agt ? oi1 : i1;
        const float w2  = agt ? b2 : ob2;  const int wi2 = agt ? i2 : oi2;
        const bool sgt = (l1 > w2) || (l1 == w2 && li1 < wi2);
        b1 = w1;  i1 = wi1;
        b2 = sgt ? l1 : w2;  i2 = sgt ? li1 : wi2;
    }

    // Exact fp64 rescreen of the two candidates (global fp32), reusing zv.
    const float* __restrict__ cbh = cb + (size_t)h * MM * DH;
    const float* __restrict__ c1  = cbh + (size_t)i1 * DH;
    const float* __restrict__ c2  = cbh + (size_t)i2 * DH;
    double d1 = 0.0, d2 = 0.0;
#pragma unroll
    for (int j = 0; j < 8; ++j) {
        const int k0 = g * 8 + j, k1 = 32 + g * 8 + j;
        d1 = fma((double)zv[j],     (double)c1[k0], d1);
        d1 = fma((double)zv[8 + j], (double)c1[k1], d1);
        d2 = fma((double)zv[j],     (double)c2[k0], d2);
        d2 = fma((double)zv[8 + j], (double)c2[k1], d2);
    }
    d1 += __shfl_xor(d1, 16, 64);  d1 += __shfl_xor(d1, 32, 64);
    d2 += __shfl_xor(d2, 16, 64);  d2 += __shfl_xor(d2, 32, 64);
    const int best = (d2 > d1 || (d2 == d1 && i2 < i1)) ? i2 : i1;

    // Epilogue: quantized row, squared error, idx. NO segment-sum atomics.
    const float* __restrict__ cq  = cbh + (size_t)best * DH;
    float* __restrict__ zqp  = zq_out + ((size_t)(b * DD + h * DH) * LL + l);
    float err = 0.f;
#pragma unroll
    for (int j = 0; j < 8; ++j) {
        const int k0 = g * 8 + j, k1 = 32 + g * 8 + j;
        const float q0 = cq[k0], q1 = cq[k1];
        zqp[(size_t)k0 * LL] = q0;
        zqp[(size_t)k1 * LL] = q1;
        const float e0 = zv[j] - q0, e1 = zv[8 + j] - q1;
        err = fmaf(e0, e0, err);
        err = fmaf(e1, e1, err);
    }
    if (g == 0) idx_out[((size_t)b * HH + h) * LL + l] = (float)best;
#pragma unroll
    for (int off = 32; off; off >>= 1) err += __shfl_xor(err, off, 64);
    if (lane == 0) atomicAdd(sse, err);
}

// One wave per (h,m) code: scan head-h's 16384 indices (coalesced, L2-hot),
// gather matching z rows (lane k accumulates element k -> sums lane-resident),
// then slerp + rms_norm update. Replaces 8.4M global atomics with ~reading z once.
__global__ __launch_bounds__(256) void vq_update_kernel(
    const float* __restrict__ z,        // [B, D, L]
    const float* __restrict__ cb,       // [H, M, DH]
    const float* __restrict__ idx,      // [B, H, L] as float
    const float* __restrict__ sse,
    float* __restrict__ cb_out,
    float* __restrict__ loss_out)
{
    if (blockIdx.x == 0 && threadIdx.x == 0) {
        loss_out[0] = 1.25f * sse[0] / (float)TOTAL_ELEMS;
    }
    const int row  = blockIdx.x * 4 + (threadIdx.x >> 6);   // h*MM + m
    const int lane = threadIdx.x & 63;
    const int h    = row >> 10;
    const int m    = row & (MM - 1);
    const float fm = (float)m;

    float acc = 0.f;
    int   cnt = 0;
#pragma unroll 1
    for (int b = 0; b < BZ; ++b) {
        const float* __restrict__ ip = idx + ((size_t)(b * HH + h)) * LL;
        const float* __restrict__ zb = z + ((size_t)(b * DD + h * DH + lane)) * LL;
#pragma unroll 1
        for (int it = 0; it < LL / 256; ++it) {
            const float4 iv = *(const float4*)(ip + it * 256 + lane * 4);
#pragma unroll
            for (int j = 0; j < 4; ++j) {
                const float ivj = (&iv.x)[j];
                unsigned long long mask = __ballot(ivj == fm);
                cnt += (int)__popcll(mask);
                while (mask) {
                    const int src = (int)__ffsll((long long)mask) - 1;
                    mask &= mask - 1;
                    const int l = it * 256 + src * 4 + j;
                    acc += zb[l];           // lane k gathers z[b, h*64+k, l]
                }
            }
        }
    }

    const float cf   = (float)cnt;
    const float c    = cb[(size_t)row * DH + lane];
    const float mean = acc / fmaxf(cf, 1.0f);

    float dot = mean * c;
    float nl  = mean * mean;
    float nh  = c * c;
#pragma unroll
    for (int off = 32; off; off >>= 1) {
        dot += __shfl_xor(dot, off, 64);
        nl  += __shfl_xor(nl,  off, 64);
        nh  += __shfl_xor(nh,  off, 64);
    }

    float cosv = dot / fmaxf(sqrtf(nl) * sqrtf(nh), 1e-8f);
    cosv = fminf(fmaxf(cosv, -0.9999999f), 0.9999999f);
    const float omega = acosf(cosv);
    const float so    = sinf(omega);
    float outv = (mean * sinf(0.01f * omega) + c * sinf(0.99f * omega)) / so;

    float ms = outv * outv;
#pragma unroll
    for (int off = 32; off; off >>= 1) ms += __shfl_xor(ms, off, 64);
    ms = ms * (1.0f / (float)DH) + 1.1920929e-07f;
    const float normed = outv / sqrtf(ms);

    cb_out[(size_t)row * DH + lane] = (cnt > 0) ? normed : c;
}

extern "C" void kernel_launch(void* const* d_in, const int* in_sizes, int n_in,
                              void* d_out, int out_size, void* d_ws, size_t ws_size,
                              hipStream_t stream) {
    const float* z  = (const float*)d_in[0];
    const float* cb = (const float*)d_in[1];
    float* out = (float*)d_out;
    float* ws  = (float*)d_ws;
    short* cb_hi = (short*)((char*)d_ws + WS_PLANES_BYTE);
    short* cb_lo = cb_hi + (size_t)HH * MM * DH;

    hipMemsetAsync(d_ws, 0, 64, stream);   // sse

    cvt_cb_kernel<<<(HH * MM * DH / 8) / 256, 256, 0, stream>>>(cb, cb_hi, cb_lo);

    dim3 gridA(NN / 128, HH);   // (128, 8) = 1024 blocks x 8 waves
    vq_assign_kernel<<<gridA, 512, 0, stream>>>(
        z, cb, cb_hi, cb_lo,
        out + OFF_ZQ, out + OFF_IDX, ws);

    dim3 gridB((HH * MM) / 4);  // 2048 blocks x 4 waves (one wave per code)
    vq_update_kernel<<<gridB, 256, 0, stream>>>(
        z, cb, out + OFF_IDX, ws,
        out + OFF_CB, out + OFF_LOSS);
}

// Round 9
// 281.313 us; speedup vs baseline: 3.3886x; 1.0163x over previous
//
#include <hip/hip_runtime.h>
#include <hip/hip_bf16.h>
#include <math.h>

// Problem constants
#define BZ   8
#define DD   512
#define LL   2048
#define HH   8
#define MM   1024
#define DH   64
#define NN   (BZ * LL)               // 16384 rows per head
#define TOTAL_ELEMS (HH * NN * DH)   // 8388608

// d_out layout (floats): [z_q (8388608)] [vq_loss (1)] [indices (131072)] [codebooks (524288)]
#define OFF_ZQ   0
#define OFF_LOSS 8388608
#define OFF_IDX  8388609
#define OFF_CB   8519681

// d_ws layout: [sse (1 float) pad to 64B] | bf16-hi plane (524288 shorts) | bf16-lo plane.
#define WS_PLANES_BYTE 64

typedef __attribute__((ext_vector_type(8))) short short8;
typedef __attribute__((ext_vector_type(4))) float float4v;

__device__ __forceinline__ unsigned short f2bf(float f) {
    unsigned int u = __builtin_bit_cast(unsigned int, f);
    u += 0x7FFFu + ((u >> 16) & 1u);          // RNE
    return (unsigned short)(u >> 16);
}
__device__ __forceinline__ float bf2f(unsigned short s) {
    unsigned int u = ((unsigned int)s) << 16;
    return __builtin_bit_cast(float, u);
}

__device__ __forceinline__ void gload16(const short* g, short* l) {
    __builtin_amdgcn_global_load_lds(
        (const __attribute__((address_space(1))) unsigned int*)g,
        (__attribute__((address_space(3))) unsigned int*)l, 16, 0, 0);
}

// Prep: fp32 codebook -> bf16 hi/lo planes, 16B chunks XOR-swizzled within each
// 128B row (chunk c stored at c^(row&7)) so unpadded LDS tiles read conflict-free.
__global__ __launch_bounds__(256) void cvt_cb_kernel(
    const float* __restrict__ cb, short* __restrict__ hip_, short* __restrict__ lop_)
{
    const int tid = blockIdx.x * 256 + threadIdx.x;
    const int c   = tid & 7;
    const int row = tid >> 3;                          // h*MM + m
    const float* __restrict__ src = cb + (size_t)row * DH + c * 8;
    short hs[8], ls[8];
#pragma unroll
    for (int j = 0; j < 8; ++j) {
        const float f = src[j];
        const unsigned short hv = f2bf(f);
        hs[j] = (short)hv;
        ls[j] = (short)f2bf(f - bf2f(hv));
    }
    const int dst = row * DH + ((c ^ (row & 7)) * 8);
    *(short8*)&hip_[dst] = *(short8*)hs;
    *(short8*)&lop_[dst] = *(short8*)ls;
}

// R8 lesson: kernel A's residual 90us over the pipe-busy floor is the top-2
// selection chain: 256 values/lane funnel into ONE (b1,b2,i1,i2) dependency
// chain (~8 dependent VALU ops x 4cyc each = ~8k serial cyc/wave). Fix: 4
// independent top-2 chains (one per s-subtile class), merged once at the end.
__global__ __launch_bounds__(512) void vq_assign_kernel(
    const float* __restrict__ z,          // [B, D, L]
    const float* __restrict__ cb,         // [H, M, DH] fp32 (rescreen/epilogue)
    const short* __restrict__ cb_hi,      // bf16 hi, swizzled
    const short* __restrict__ cb_lo,      // bf16 lo, swizzled
    float* __restrict__ zq_out,
    float* __restrict__ idx_out,
    float* __restrict__ sse)
{
    __shared__ __align__(16) short hi_lds[2][64 * DH];   // 2 x 8 KB
    __shared__ __align__(16) short lo_lds[2][64 * DH];   // 2 x 8 KB

    const int t    = threadIdx.x;
    const int h    = blockIdx.y;
    const int lane = t & 63;
    const int g    = lane >> 4;          // quad 0..3
    const int nloc = lane & 15;
    const int w    = t >> 6;             // wave 0..7

    // This lane's z row (16 rows per wave, 128 per block); 4 quads share a row.
    const int r = blockIdx.x * 128 + w * 16 + nloc;
    const int b = r >> 11;
    const int l = r & (LL - 1);
    const float* __restrict__ zbase = z + ((size_t)(b * DD + h * DH) * LL + l);

    // B-fragment z values: zv[j] <-> k=g*8+j, zv[8+j] <-> k=32+g*8+j.
    float zv[16];
#pragma unroll
    for (int j = 0; j < 8; ++j) zv[j]     = zbase[(size_t)(g * 8 + j) * LL];
#pragma unroll
    for (int j = 0; j < 8; ++j) zv[8 + j] = zbase[(size_t)(32 + g * 8 + j) * LL];

    short bh[16], bl[16];
#pragma unroll
    for (int j = 0; j < 16; ++j) {
        const unsigned short hv = f2bf(zv[j]);
        bh[j] = (short)hv;
        bl[j] = (short)f2bf(zv[j] - bf2f(hv));
    }
    const short8 Bh0 = *(short8*)&bh[0], Bh1 = *(short8*)&bh[8];
    const short8 Bl0 = *(short8*)&bl[0], Bl1 = *(short8*)&bl[8];

    const short* __restrict__ gh = cb_hi + (size_t)h * MM * DH;
    const short* __restrict__ gl = cb_lo + (size_t)h * MM * DH;

    // Stage one 64-row tile (8 KB hi + 8 KB lo): 512 threads x 16B each plane.
    auto stage = [&](int mt, int buf) {
        const short* sh = gh + (size_t)mt * 64 * DH;
        const short* sl = gl + (size_t)mt * 64 * DH;
        gload16(sh + t * 8, &hi_lds[buf][t * 8]);
        gload16(sl + t * 8, &lo_lds[buf][t * 8]);
    };

    stage(0, 0);

    // 4 independent top-2 chains (one per s class) -> 4x ILP on selection.
    float b1c[4], b2c[4];
    int   i1c[4], i2c[4];
#pragma unroll
    for (int s = 0; s < 4; ++s) { b1c[s] = -1e30f; b2c[s] = -1e30f; i1c[s] = 0; i2c[s] = 0; }

    const int sw8 = nloc & 7;

    for (int mt = 0; mt < MM / 64; ++mt) {
        __syncthreads();                       // vmcnt(0) drains exactly tile mt's DMA
        if (mt + 1 < MM / 64) stage(mt + 1, (mt + 1) & 1);
        const int buf = mt & 1;

#pragma unroll
        for (int s = 0; s < 4; ++s) {
            const short* hrow = &hi_lds[buf][(s * 16 + nloc) * DH];
            const short* lrow = &lo_lds[buf][(s * 16 + nloc) * DH];
            const short8 Ah0 = *(const short8*)&hrow[((g)     ^ sw8) * 8];
            const short8 Ah1 = *(const short8*)&hrow[((g + 4) ^ sw8) * 8];
            const short8 Al0 = *(const short8*)&lrow[((g)     ^ sw8) * 8];
            const short8 Al1 = *(const short8*)&lrow[((g + 4) ^ sw8) * 8];

            float4v acc = {0.f, 0.f, 0.f, 0.f};
            acc = __builtin_amdgcn_mfma_f32_16x16x32_bf16(Ah0, Bh0, acc, 0, 0, 0);
            acc = __builtin_amdgcn_mfma_f32_16x16x32_bf16(Ah1, Bh1, acc, 0, 0, 0);
            acc = __builtin_amdgcn_mfma_f32_16x16x32_bf16(Ah0, Bl0, acc, 0, 0, 0);
            acc = __builtin_amdgcn_mfma_f32_16x16x32_bf16(Ah1, Bl1, acc, 0, 0, 0);
            acc = __builtin_amdgcn_mfma_f32_16x16x32_bf16(Al0, Bh0, acc, 0, 0, 0);
            acc = __builtin_amdgcn_mfma_f32_16x16x32_bf16(Al1, Bh1, acc, 0, 0, 0);

            const int mbase = mt * 64 + s * 16 + g * 4;
#pragma unroll
            for (int reg = 0; reg < 4; ++reg) {
                const float v = acc[reg];
                const int   m = mbase + reg;
                const bool gt1 = v > b1c[s];
                const bool gt2 = v > b2c[s];
                b2c[s] = gt1 ? b1c[s] : (gt2 ? v : b2c[s]);
                i2c[s] = gt1 ? i1c[s] : (gt2 ? m : i2c[s]);
                b1c[s] = gt1 ? v : b1c[s];
                i1c[s] = gt1 ? m : i1c[s];
            }
        }
    }

    // Merge the 4 chains into one top-2 (value desc, index-asc tie-break).
    float b1 = b1c[0], b2 = b2c[0];
    int   i1 = i1c[0], i2 = i2c[0];
#pragma unroll
    for (int s = 1; s < 4; ++s) {
        const float ob1 = b1c[s], ob2 = b2c[s];
        const int   oi1 = i1c[s], oi2 = i2c[s];
        const bool agt = (b1 > ob1) || (b1 == ob1 && i1 < oi1);
        const float w1 = agt ? b1 : ob1;  const int wi1 = agt ? i1 : oi1;
        const float l1 = agt ? ob1 : b1;  const int li1 = agt ? oi1 : i1;
        const float w2 = agt ? b2 : ob2;  const int wi2 = agt ? i2 : oi2;
        const bool sgt = (l1 > w2) || (l1 == w2 && li1 < wi2);
        b1 = w1;  i1 = wi1;
        b2 = sgt ? l1 : w2;  i2 = sgt ? li1 : wi2;
    }

    // Merge top-2 across the 4 quads holding the same row.
#pragma unroll
    for (int off = 16; off <= 32; off <<= 1) {
        float ob1 = __shfl_xor(b1, off, 64);
        int   oi1 = __shfl_xor(i1, off, 64);
        float ob2 = __shfl_xor(b2, off, 64);
        int   oi2 = __shfl_xor(i2, off, 64);
        const bool agt = (b1 > ob1) || (b1 == ob1 && i1 < oi1);
        const float w1  = agt ? b1 : ob1;  const int wi1 = agt ? i1 : oi1;
        const float l1  = agt ? ob1 : b1;  const int li1 = agt ? oi1 : i1;
        const float w2  = agt ? b2 : ob2;  const int wi2 = agt ? i2 : oi2;
        const bool sgt = (l1 > w2) || (l1 == w2 && li1 < wi2);
        b1 = w1;  i1 = wi1;
        b2 = sgt ? l1 : w2;  i2 = sgt ? li1 : wi2;
    }

    // Exact fp64 rescreen of the two candidates (global fp32), reusing zv.
    const float* __restrict__ cbh = cb + (size_t)h * MM * DH;
    const float* __restrict__ c1  = cbh + (size_t)i1 * DH;
    const float* __restrict__ c2  = cbh + (size_t)i2 * DH;
    double d1 = 0.0, d2 = 0.0;
#pragma unroll
    for (int j = 0; j < 8; ++j) {
        const int k0 = g * 8 + j, k1 = 32 + g * 8 + j;
        d1 = fma((double)zv[j],     (double)c1[k0], d1);
        d1 = fma((double)zv[8 + j], (double)c1[k1], d1);
        d2 = fma((double)zv[j],     (double)c2[k0], d2);
        d2 = fma((double)zv[8 + j], (double)c2[k1], d2);
    }
    d1 += __shfl_xor(d1, 16, 64);  d1 += __shfl_xor(d1, 32, 64);
    d2 += __shfl_xor(d2, 16, 64);  d2 += __shfl_xor(d2, 32, 64);
    const int best = (d2 > d1 || (d2 == d1 && i2 < i1)) ? i2 : i1;

    // Epilogue: quantized row, squared error, idx. No segment-sum atomics.
    const float* __restrict__ cq  = cbh + (size_t)best * DH;
    float* __restrict__ zqp  = zq_out + ((size_t)(b * DD + h * DH) * LL + l);
    float err = 0.f;
#pragma unroll
    for (int j = 0; j < 8; ++j) {
        const int k0 = g * 8 + j, k1 = 32 + g * 8 + j;
        const float q0 = cq[k0], q1 = cq[k1];
        zqp[(size_t)k0 * LL] = q0;
        zqp[(size_t)k1 * LL] = q1;
        const float e0 = zv[j] - q0, e1 = zv[8 + j] - q1;
        err = fmaf(e0, e0, err);
        err = fmaf(e1, e1, err);
    }
    if (g == 0) idx_out[((size_t)b * HH + h) * LL + l] = (float)best;
#pragma unroll
    for (int off = 32; off; off >>= 1) err += __shfl_xor(err, off, 64);
    if (lane == 0) atomicAdd(sse, err);
}

// One wave per (h,m) code: scan head-h's 16384 indices (coalesced, L2-hot),
// gather matching z rows (lane k accumulates element k -> sums lane-resident),
// then slerp + rms_norm update.
__global__ __launch_bounds__(256) void vq_update_kernel(
    const float* __restrict__ z,        // [B, D, L]
    const float* __restrict__ cb,       // [H, M, DH]
    const float* __restrict__ idx,      // [B, H, L] as float
    const float* __restrict__ sse,
    float* __restrict__ cb_out,
    float* __restrict__ loss_out)
{
    if (blockIdx.x == 0 && threadIdx.x == 0) {
        loss_out[0] = 1.25f * sse[0] / (float)TOTAL_ELEMS;
    }
    const int row  = blockIdx.x * 4 + (threadIdx.x >> 6);   // h*MM + m
    const int lane = threadIdx.x & 63;
    const int h    = row >> 10;
    const int m    = row & (MM - 1);
    const float fm = (float)m;

    float acc = 0.f;
    int   cnt = 0;
#pragma unroll 1
    for (int b = 0; b < BZ; ++b) {
        const float* __restrict__ ip = idx + ((size_t)(b * HH + h)) * LL;
        const float* __restrict__ zb = z + ((size_t)(b * DD + h * DH + lane)) * LL;
#pragma unroll 1
        for (int it = 0; it < LL / 256; ++it) {
            const float4 iv = *(const float4*)(ip + it * 256 + lane * 4);
#pragma unroll
            for (int j = 0; j < 4; ++j) {
                const float ivj = (&iv.x)[j];
                unsigned long long mask = __ballot(ivj == fm);
                cnt += (int)__popcll(mask);
                while (mask) {
                    const int src = (int)__ffsll((long long)mask) - 1;
                    mask &= mask - 1;
                    const int l = it * 256 + src * 4 + j;
                    acc += zb[l];           // lane k gathers z[b, h*64+k, l]
                }
            }
        }
    }

    const float cf   = (float)cnt;
    const float c    = cb[(size_t)row * DH + lane];
    const float mean = acc / fmaxf(cf, 1.0f);

    float dot = mean * c;
    float nl  = mean * mean;
    float nh  = c * c;
#pragma unroll
    for (int off = 32; off; off >>= 1) {
        dot += __shfl_xor(dot, off, 64);
        nl  += __shfl_xor(nl,  off, 64);
        nh  += __shfl_xor(nh,  off, 64);
    }

    float cosv = dot / fmaxf(sqrtf(nl) * sqrtf(nh), 1e-8f);
    cosv = fminf(fmaxf(cosv, -0.9999999f), 0.9999999f);
    const float omega = acosf(cosv);
    const float so    = sinf(omega);
    float outv = (mean * sinf(0.01f * omega) + c * sinf(0.99f * omega)) / so;

    float ms = outv * outv;
#pragma unroll
    for (int off = 32; off; off >>= 1) ms += __shfl_xor(ms, off, 64);
    ms = ms * (1.0f / (float)DH) + 1.1920929e-07f;
    const float normed = outv / sqrtf(ms);

    cb_out[(size_t)row * DH + lane] = (cnt > 0) ? normed : c;
}

extern "C" void kernel_launch(void* const* d_in, const int* in_sizes, int n_in,
                              void* d_out, int out_size, void* d_ws, size_t ws_size,
                              hipStream_t stream) {
    const float* z  = (const float*)d_in[0];
    const float* cb = (const float*)d_in[1];
    float* out = (float*)d_out;
    float* ws  = (float*)d_ws;
    short* cb_hi = (short*)((char*)d_ws + WS_PLANES_BYTE);
    short* cb_lo = cb_hi + (size_t)HH * MM * DH;

    hipMemsetAsync(d_ws, 0, 64, stream);   // sse

    cvt_cb_kernel<<<(HH * MM * DH / 8) / 256, 256, 0, stream>>>(cb, cb_hi, cb_lo);

    dim3 gridA(NN / 128, HH);   // (128, 8) = 1024 blocks x 8 waves
    vq_assign_kernel<<<gridA, 512, 0, stream>>>(
        z, cb, cb_hi, cb_lo,
        out + OFF_ZQ, out + OFF_IDX, ws);

    dim3 gridB((HH * MM) / 4);  // 2048 blocks x 4 waves (one wave per code)
    vq_update_kernel<<<gridB, 256, 0, stream>>>(
        z, cb, out + OFF_IDX, ws,
        out + OFF_CB, out + OFF_LOSS);
}

// Round 10
// 258.055 us; speedup vs baseline: 3.6940x; 1.0901x over previous
//
#include <hip/hip_runtime.h>
#include <hip/hip_bf16.h>
#include <math.h>

// Problem constants
#define BZ   8
#define DD   512
#define LL   2048
#define HH   8
#define MM   1024
#define DH   64
#define NN   (BZ * LL)               // 16384 rows per head
#define TOTAL_ELEMS (HH * NN * DH)   // 8388608

// d_out layout (floats): [z_q (8388608)] [vq_loss (1)] [indices (131072)] [codebooks (524288)]
#define OFF_ZQ   0
#define OFF_LOSS 8388608
#define OFF_IDX  8388609
#define OFF_CB   8519681

// d_ws layout: [sse: 64B] [cb_hi: 1MB] [cb_lo: 1MB] [z_split fp32: 33.5MB, optional]
#define WS_PLANES_BYTE 64
#define WS_ZSPLIT_BYTE (64 + 2u * HH * MM * DH * 2)                   // 2,097,216
#define WS_NEED_FAT    (WS_ZSPLIT_BYTE + (size_t)HH * NN * DH * 4)    // ~35.7 MB

typedef __attribute__((ext_vector_type(8))) short short8;
typedef __attribute__((ext_vector_type(4))) float float4v;

__device__ __forceinline__ unsigned short f2bf(float f) {
    unsigned int u = __builtin_bit_cast(unsigned int, f);
    u += 0x7FFFu + ((u >> 16) & 1u);          // RNE
    return (unsigned short)(u >> 16);
}
__device__ __forceinline__ float bf2f(unsigned short s) {
    unsigned int u = ((unsigned int)s) << 16;
    return __builtin_bit_cast(float, u);
}

__device__ __forceinline__ void gload16(const short* g, short* l) {
    __builtin_amdgcn_global_load_lds(
        (const __attribute__((address_space(1))) unsigned int*)g,
        (__attribute__((address_space(3))) unsigned int*)l, 16, 0, 0);
}

// Prep: fp32 codebook -> bf16 hi/lo planes, 16B chunks XOR-swizzled within each
// 128B row (chunk c stored at c^(row&7)) so unpadded LDS tiles read conflict-free.
__global__ __launch_bounds__(256) void cvt_cb_kernel(
    const float* __restrict__ cb, short* __restrict__ hip_, short* __restrict__ lop_)
{
    const int tid = blockIdx.x * 256 + threadIdx.x;
    const int c   = tid & 7;
    const int row = tid >> 3;                          // h*MM + m
    const float* __restrict__ src = cb + (size_t)row * DH + c * 8;
    short hs[8], ls[8];
#pragma unroll
    for (int j = 0; j < 8; ++j) {
        const float f = src[j];
        const unsigned short hv = f2bf(f);
        hs[j] = (short)hv;
        ls[j] = (short)f2bf(f - bf2f(hv));
    }
    const int dst = row * DH + ((c ^ (row & 7)) * 8);
    *(short8*)&hip_[dst] = *(short8*)hs;
    *(short8*)&lop_[dst] = *(short8*)ls;
}

// R9 lesson: A has plateaued ~150us (selection-ILP change was neutral). The
// hidden cost was B: gathering z[b,h*64+k,l] is 64 cache lines per match.
// A now also writes z_split [H,N,64] fp32 contiguous (if ws_size permits), so
// B's gather is 256B contiguous per match.
__global__ __launch_bounds__(512) void vq_assign_kernel(
    const float* __restrict__ z,          // [B, D, L]
    const float* __restrict__ cb,         // [H, M, DH] fp32 (rescreen/epilogue)
    const short* __restrict__ cb_hi,      // bf16 hi, swizzled
    const short* __restrict__ cb_lo,      // bf16 lo, swizzled
    float* __restrict__ zq_out,
    float* __restrict__ idx_out,
    float* __restrict__ sse,
    float* __restrict__ zs)               // [H, N, DH] or null
{
    __shared__ __align__(16) short hi_lds[2][64 * DH];   // 2 x 8 KB
    __shared__ __align__(16) short lo_lds[2][64 * DH];   // 2 x 8 KB

    const int t    = threadIdx.x;
    const int h    = blockIdx.y;
    const int lane = t & 63;
    const int g    = lane >> 4;          // quad 0..3
    const int nloc = lane & 15;
    const int w    = t >> 6;             // wave 0..7

    // This lane's z row (16 rows per wave, 128 per block); 4 quads share a row.
    const int r = blockIdx.x * 128 + w * 16 + nloc;
    const int b = r >> 11;
    const int l = r & (LL - 1);
    const float* __restrict__ zbase = z + ((size_t)(b * DD + h * DH) * LL + l);

    // B-fragment z values: zv[j] <-> k=g*8+j, zv[8+j] <-> k=32+g*8+j.
    float zv[16] __attribute__((aligned(16)));
#pragma unroll
    for (int j = 0; j < 8; ++j) zv[j]     = zbase[(size_t)(g * 8 + j) * LL];
#pragma unroll
    for (int j = 0; j < 8; ++j) zv[8 + j] = zbase[(size_t)(32 + g * 8 + j) * LL];

    // Optional: write this row's chunk to z_split [H, N, 64] for the fast B gather.
    if (zs) {
        float* __restrict__ zr_ = zs + ((size_t)h * NN + r) * DH;
        *(float4*)&zr_[g * 8]          = *(const float4*)&zv[0];
        *(float4*)&zr_[g * 8 + 4]      = *(const float4*)&zv[4];
        *(float4*)&zr_[32 + g * 8]     = *(const float4*)&zv[8];
        *(float4*)&zr_[32 + g * 8 + 4] = *(const float4*)&zv[12];
    }

    short bh[16], bl[16];
#pragma unroll
    for (int j = 0; j < 16; ++j) {
        const unsigned short hv = f2bf(zv[j]);
        bh[j] = (short)hv;
        bl[j] = (short)f2bf(zv[j] - bf2f(hv));
    }
    const short8 Bh0 = *(short8*)&bh[0], Bh1 = *(short8*)&bh[8];
    const short8 Bl0 = *(short8*)&bl[0], Bl1 = *(short8*)&bl[8];

    const short* __restrict__ gh = cb_hi + (size_t)h * MM * DH;
    const short* __restrict__ gl = cb_lo + (size_t)h * MM * DH;

    // Stage one 64-row tile (8 KB hi + 8 KB lo): 512 threads x 16B each plane.
    auto stage = [&](int mt, int buf) {
        const short* sh = gh + (size_t)mt * 64 * DH;
        const short* sl = gl + (size_t)mt * 64 * DH;
        gload16(sh + t * 8, &hi_lds[buf][t * 8]);
        gload16(sl + t * 8, &lo_lds[buf][t * 8]);
    };

    stage(0, 0);

    // 4 independent top-2 chains (one per s class), merged at the end.
    float b1c[4], b2c[4];
    int   i1c[4], i2c[4];
#pragma unroll
    for (int s = 0; s < 4; ++s) { b1c[s] = -1e30f; b2c[s] = -1e30f; i1c[s] = 0; i2c[s] = 0; }

    const int sw8 = nloc & 7;

    for (int mt = 0; mt < MM / 64; ++mt) {
        __syncthreads();                       // vmcnt(0) drains exactly tile mt's DMA
        if (mt + 1 < MM / 64) stage(mt + 1, (mt + 1) & 1);
        const int buf = mt & 1;

#pragma unroll
        for (int s = 0; s < 4; ++s) {
            const short* hrow = &hi_lds[buf][(s * 16 + nloc) * DH];
            const short* lrow = &lo_lds[buf][(s * 16 + nloc) * DH];
            const short8 Ah0 = *(const short8*)&hrow[((g)     ^ sw8) * 8];
            const short8 Ah1 = *(const short8*)&hrow[((g + 4) ^ sw8) * 8];
            const short8 Al0 = *(const short8*)&lrow[((g)     ^ sw8) * 8];
            const short8 Al1 = *(const short8*)&lrow[((g + 4) ^ sw8) * 8];

            float4v acc = {0.f, 0.f, 0.f, 0.f};
            acc = __builtin_amdgcn_mfma_f32_16x16x32_bf16(Ah0, Bh0, acc, 0, 0, 0);
            acc = __builtin_amdgcn_mfma_f32_16x16x32_bf16(Ah1, Bh1, acc, 0, 0, 0);
            acc = __builtin_amdgcn_mfma_f32_16x16x32_bf16(Ah0, Bl0, acc, 0, 0, 0);
            acc = __builtin_amdgcn_mfma_f32_16x16x32_bf16(Ah1, Bl1, acc, 0, 0, 0);
            acc = __builtin_amdgcn_mfma_f32_16x16x32_bf16(Al0, Bh0, acc, 0, 0, 0);
            acc = __builtin_amdgcn_mfma_f32_16x16x32_bf16(Al1, Bh1, acc, 0, 0, 0);

            const int mbase = mt * 64 + s * 16 + g * 4;
#pragma unroll
            for (int reg = 0; reg < 4; ++reg) {
                const float v = acc[reg];
                const int   m = mbase + reg;
                const bool gt1 = v > b1c[s];
                const bool gt2 = v > b2c[s];
                b2c[s] = gt1 ? b1c[s] : (gt2 ? v : b2c[s]);
                i2c[s] = gt1 ? i1c[s] : (gt2 ? m : i2c[s]);
                b1c[s] = gt1 ? v : b1c[s];
                i1c[s] = gt1 ? m : i1c[s];
            }
        }
    }

    // Merge the 4 chains into one top-2 (value desc, index-asc tie-break).
    float b1 = b1c[0], b2 = b2c[0];
    int   i1 = i1c[0], i2 = i2c[0];
#pragma unroll
    for (int s = 1; s < 4; ++s) {
        const float ob1 = b1c[s], ob2 = b2c[s];
        const int   oi1 = i1c[s], oi2 = i2c[s];
        const bool agt = (b1 > ob1) || (b1 == ob1 && i1 < oi1);
        const float w1 = agt ? b1 : ob1;  const int wi1 = agt ? i1 : oi1;
        const float l1 = agt ? ob1 : b1;  const int li1 = agt ? oi1 : i1;
        const float w2 = agt ? b2 : ob2;  const int wi2 = agt ? i2 : oi2;
        const bool sgt = (l1 > w2) || (l1 == w2 && li1 < wi2);
        b1 = w1;  i1 = wi1;
        b2 = sgt ? l1 : w2;  i2 = sgt ? li1 : wi2;
    }

    // Merge top-2 across the 4 quads holding the same row.
#pragma unroll
    for (int off = 16; off <= 32; off <<= 1) {
        float ob1 = __shfl_xor(b1, off, 64);
        int   oi1 = __shfl_xor(i1, off, 64);
        float ob2 = __shfl_xor(b2, off, 64);
        int   oi2 = __shfl_xor(i2, off, 64);
        const bool agt = (b1 > ob1) || (b1 == ob1 && i1 < oi1);
        const float w1  = agt ? b1 : ob1;  const int wi1 = agt ? i1 : oi1;
        const float l1  = agt ? ob1 : b1;  const int li1 = agt ? oi1 : i1;
        const float w2  = agt ? b2 : ob2;  const int wi2 = agt ? i2 : oi2;
        const bool sgt = (l1 > w2) || (l1 == w2 && li1 < wi2);
        b1 = w1;  i1 = wi1;
        b2 = sgt ? l1 : w2;  i2 = sgt ? li1 : wi2;
    }

    // Exact fp64 rescreen of the two candidates (global fp32), reusing zv.
    const float* __restrict__ cbh = cb + (size_t)h * MM * DH;
    const float* __restrict__ c1  = cbh + (size_t)i1 * DH;
    const float* __restrict__ c2  = cbh + (size_t)i2 * DH;
    double d1 = 0.0, d2 = 0.0;
#pragma unroll
    for (int j = 0; j < 8; ++j) {
        const int k0 = g * 8 + j, k1 = 32 + g * 8 + j;
        d1 = fma((double)zv[j],     (double)c1[k0], d1);
        d1 = fma((double)zv[8 + j], (double)c1[k1], d1);
        d2 = fma((double)zv[j],     (double)c2[k0], d2);
        d2 = fma((double)zv[8 + j], (double)c2[k1], d2);
    }
    d1 += __shfl_xor(d1, 16, 64);  d1 += __shfl_xor(d1, 32, 64);
    d2 += __shfl_xor(d2, 16, 64);  d2 += __shfl_xor(d2, 32, 64);
    const int best = (d2 > d1 || (d2 == d1 && i2 < i1)) ? i2 : i1;

    // Epilogue: quantized row, squared error, idx. No segment-sum atomics.
    const float* __restrict__ cq  = cbh + (size_t)best * DH;
    float* __restrict__ zqp  = zq_out + ((size_t)(b * DD + h * DH) * LL + l);
    float err = 0.f;
#pragma unroll
    for (int j = 0; j < 8; ++j) {
        const int k0 = g * 8 + j, k1 = 32 + g * 8 + j;
        const float q0 = cq[k0], q1 = cq[k1];
        zqp[(size_t)k0 * LL] = q0;
        zqp[(size_t)k1 * LL] = q1;
        const float e0 = zv[j] - q0, e1 = zv[8 + j] - q1;
        err = fmaf(e0, e0, err);
        err = fmaf(e1, e1, err);
    }
    if (g == 0) idx_out[((size_t)b * HH + h) * LL + l] = (float)best;
#pragma unroll
    for (int off = 32; off; off >>= 1) err += __shfl_xor(err, off, 64);
    if (lane == 0) atomicAdd(sse, err);
}

// One wave per (h,m) code: scan head-h's 16384 indices (coalesced, L2-hot),
// gather matching z rows, slerp + rms_norm update. If zs != null the gather is
// 256B-contiguous per match (z_split); else strided fallback from z.
__global__ __launch_bounds__(256) void vq_update_kernel(
    const float* __restrict__ z,        // [B, D, L]
    const float* __restrict__ zs,       // [H, N, DH] or null
    const float* __restrict__ cb,       // [H, M, DH]
    const float* __restrict__ idx,      // [B, H, L] as float
    const float* __restrict__ sse,
    float* __restrict__ cb_out,
    float* __restrict__ loss_out)
{
    if (blockIdx.x == 0 && threadIdx.x == 0) {
        loss_out[0] = 1.25f * sse[0] / (float)TOTAL_ELEMS;
    }
    const int row  = blockIdx.x * 4 + (threadIdx.x >> 6);   // h*MM + m
    const int lane = threadIdx.x & 63;
    const int h    = row >> 10;
    const int m    = row & (MM - 1);
    const float fm = (float)m;

    float acc = 0.f;
    int   cnt = 0;
#pragma unroll 1
    for (int b = 0; b < BZ; ++b) {
        const float* __restrict__ ip  = idx + ((size_t)(b * HH + h)) * LL;
        const float* __restrict__ zb  = z + ((size_t)(b * DD + h * DH + lane)) * LL;
        const float* __restrict__ zsb = zs ? (zs + ((size_t)h * NN + (size_t)b * LL) * DH + lane)
                                          : (const float*)0;
#pragma unroll 1
        for (int it = 0; it < LL / 256; ++it) {
            const float4 iv = *(const float4*)(ip + it * 256 + lane * 4);
#pragma unroll
            for (int j = 0; j < 4; ++j) {
                const float ivj = (&iv.x)[j];
                unsigned long long mask = __ballot(ivj == fm);
                cnt += (int)__popcll(mask);
                while (mask) {
                    const int src = (int)__ffsll((long long)mask) - 1;
                    mask &= mask - 1;
                    const int l = it * 256 + src * 4 + j;
                    acc += zsb ? zsb[(size_t)l * DH]   // 256B contiguous across lanes
                               : zb[l];                // strided fallback
                }
            }
        }
    }

    const float cf   = (float)cnt;
    const float c    = cb[(size_t)row * DH + lane];
    const float mean = acc / fmaxf(cf, 1.0f);

    float dot = mean * c;
    float nl  = mean * mean;
    float nh  = c * c;
#pragma unroll
    for (int off = 32; off; off >>= 1) {
        dot += __shfl_xor(dot, off, 64);
        nl  += __shfl_xor(nl,  off, 64);
        nh  += __shfl_xor(nh,  off, 64);
    }

    float cosv = dot / fmaxf(sqrtf(nl) * sqrtf(nh), 1e-8f);
    cosv = fminf(fmaxf(cosv, -0.9999999f), 0.9999999f);
    const float omega = acosf(cosv);
    const float so    = sinf(omega);
    float outv = (mean * sinf(0.01f * omega) + c * sinf(0.99f * omega)) / so;

    float ms = outv * outv;
#pragma unroll
    for (int off = 32; off; off >>= 1) ms += __shfl_xor(ms, off, 64);
    ms = ms * (1.0f / (float)DH) + 1.1920929e-07f;
    const float normed = outv / sqrtf(ms);

    cb_out[(size_t)row * DH + lane] = (cnt > 0) ? normed : c;
}

extern "C" void kernel_launch(void* const* d_in, const int* in_sizes, int n_in,
                              void* d_out, int out_size, void* d_ws, size_t ws_size,
                              hipStream_t stream) {
    const float* z  = (const float*)d_in[0];
    const float* cb = (const float*)d_in[1];
    float* out = (float*)d_out;
    short* cb_hi = (short*)((char*)d_ws + WS_PLANES_BYTE);
    short* cb_lo = cb_hi + (size_t)HH * MM * DH;
    const bool fat = ws_size >= WS_NEED_FAT;
    float* zs = fat ? (float*)((char*)d_ws + WS_ZSPLIT_BYTE) : (float*)0;

    hipMemsetAsync(d_ws, 0, 64, stream);   // sse

    cvt_cb_kernel<<<(HH * MM * DH / 8) / 256, 256, 0, stream>>>(cb, cb_hi, cb_lo);

    dim3 gridA(NN / 128, HH);   // (128, 8) = 1024 blocks x 8 waves
    vq_assign_kernel<<<gridA, 512, 0, stream>>>(
        z, cb, cb_hi, cb_lo,
        out + OFF_ZQ, out + OFF_IDX, (float*)d_ws, zs);

    dim3 gridB((HH * MM) / 4);  // 2048 blocks x 4 waves (one wave per code)
    vq_update_kernel<<<gridB, 256, 0, stream>>>(
        z, zs, cb, out + OFF_IDX, (float*)d_ws,
        out + OFF_CB, out + OFF_LOSS);
}